// Round 3
// baseline (83.388 us; speedup 1.0000x reference)
//
#include <hip/hip_runtime.h>
#include <math.h>

// single_channel_interp (B=8, D=64, T=512, O=256)  — R2
// Two kernels:
//  A: precompute per-(b,d,t)  u = -a2*t^2 + log2(max(m,1e-30)),  w = 2*a2*t
//     (a2 = softplus(kern[d])*log2(e)) into d_ws. ~2us.
//  B: hot loop with *scalar* (wave-uniform) operands u,w,v via s_load —
//     zero LDS, zero per-lane VMEM in the loop, ~25 VGPRs.
//     arg  = w*g + u + c   (c = -a2*g^2, per-lane)
//     e1   = exp2(arg); e10 = exp2(10*arg)
//     l += e1; y += e1*v; q += e10; z += e10*v
//   1024-thread blocks: o = tid&255, quarter = tid>>8 (wave-uniform),
//   partials combined through LDS at the end.

namespace {
constexpr int kB = 8, kD = 64, kT = 512, kO = 256;
constexpr int kQ = 4;            // T-quarters per block
constexpr int kTH = kO * kQ;     // 1024 threads
constexpr int kTQ = kT / kQ;     // 128 t's per quarter
constexpr float kLOG2E = 1.4426950408889634f;
constexpr float kLN2   = 0.6931471805599453f;
constexpr int kBD = kB * kD;     // 512 rows
// ws layout (floats): U[kBD*kT] | W[kBD*kT] | A2[kBD]
constexpr size_t kWsU = 0, kWsW = (size_t)kBD * kT, kWsA2 = 2 * (size_t)kBD * kT;
}

__global__ __launch_bounds__(kT) void precompute_kernel(
    const float* __restrict__ x,     // (B, 3D, T)
    const float* __restrict__ kern,  // (D,)
    float* __restrict__ ws)
{
    const int bd = blockIdx.x;
    const int b  = bd >> 6;
    const int d  = bd & (kD - 1);
    const int t  = threadIdx.x;

    const float* base  = x + (size_t)b * (3 * kD * kT);
    const float  mm    = base[(size_t)(kD + d) * kT + t];
    const float  tt    = base[(size_t)(2 * kD + d) * kT + t];

    const float k     = kern[d];
    const float alpha = fmaxf(k, 0.0f) + log1pf(expf(-fabsf(k)));
    const float a2    = alpha * kLOG2E;

    const float lm = __builtin_amdgcn_logf(fmaxf(mm, 1e-30f)); // log2
    ws[kWsU + (size_t)bd * kT + t] = fmaf(-a2 * tt, tt, lm);
    ws[kWsW + (size_t)bd * kT + t] = 2.0f * a2 * tt;
    if (t == 0) ws[kWsA2 + bd] = a2;
}

__global__ __launch_bounds__(kTH, 8) void interp_kernel(
    const float* __restrict__ x,     // (B, 3D, T) — vals rows read uniformly
    const float* __restrict__ grid,  // (B, O)
    const float* __restrict__ ws,    // U | W | A2
    float* __restrict__ out)         // (B, 3D, O)
{
    __shared__ float s_part[kQ * 4 * kO];   // 16 KB partial combine

    const int tid = threadIdx.x;
    const int o   = tid & (kO - 1);
    const int q   = tid >> 8;        // wave-uniform (waves 0-3 -> q0, etc.)
    const int bd  = blockIdx.x;
    const int b   = bd >> 6;
    const int d   = bd & (kD - 1);

    const float* __restrict__ U = ws + kWsU + (size_t)bd * kT;
    const float* __restrict__ W = ws + kWsW + (size_t)bd * kT;
    const float* __restrict__ V =
        x + (size_t)b * (3 * kD * kT) + (size_t)d * kT;   // vals row

    const float a2 = ws[kWsA2 + bd];             // uniform -> s_load
    const float g  = grid[b * kO + o];
    const float c  = -a2 * g * g;                // per-lane

    // 2 independent chains per quantity.
    float l0 = 0.f, l1 = 0.f, y0 = 0.f, y1 = 0.f;
    float q0 = 0.f, q1 = 0.f, z0 = 0.f, z1 = 0.f;

    const int t0 = q * kTQ;
    #pragma unroll 4
    for (int t = t0; t < t0 + kTQ; t += 2) {
        // t is wave-uniform: U/W/V loads should become s_load (SMEM pipe).
        const float ua = U[t],     ub = U[t + 1];
        const float wa = W[t],     wb = W[t + 1];
        const float va = V[t],     vb = V[t + 1];

        float arg_a = ua + c;                  // v_add (sgpr, vgpr)
        arg_a = fmaf(wa, g, arg_a);            // v_fmac (sgpr, vgpr)
        float e1a  = __builtin_amdgcn_exp2f(arg_a);
        float e10a = __builtin_amdgcn_exp2f(10.0f * arg_a);
        l0 += e1a;  y0 = fmaf(e1a,  va, y0);
        q0 += e10a; z0 = fmaf(e10a, va, z0);

        float arg_b = ub + c;
        arg_b = fmaf(wb, g, arg_b);
        float e1b  = __builtin_amdgcn_exp2f(arg_b);
        float e10b = __builtin_amdgcn_exp2f(10.0f * arg_b);
        l1 += e1b;  y1 = fmaf(e1b,  vb, y1);
        q1 += e10b; z1 = fmaf(e10b, vb, z1);
    }

    const float lp = l0 + l1, yp = y0 + y1;
    const float qp = q0 + q1, zp = z0 + z1;

    s_part[(q * 4 + 0) * kO + o] = lp;
    s_part[(q * 4 + 1) * kO + o] = yp;
    s_part[(q * 4 + 2) * kO + o] = qp;
    s_part[(q * 4 + 3) * kO + o] = zp;
    __syncthreads();

    if (q == 0) {
        float l = 0.f, ya = 0.f, qs = 0.f, za = 0.f;
        #pragma unroll
        for (int j = 0; j < kQ; ++j) {
            l  += s_part[(j * 4 + 0) * kO + o];
            ya += s_part[(j * 4 + 1) * kO + o];
            qs += s_part[(j * 4 + 2) * kO + o];
            za += s_part[(j * 4 + 3) * kO + o];
        }
        const float w = __builtin_amdgcn_logf(l) * kLN2;  // logsumexp, shift=0
        float* ob = out + (size_t)b * (3 * kD * kO);
        ob[(size_t)d * kO + o]            = ya / l;
        ob[(size_t)(kD + d) * kO + o]     = w;
        ob[(size_t)(2 * kD + d) * kO + o] = za / qs;
    }
}

extern "C" void kernel_launch(void* const* d_in, const int* in_sizes, int n_in,
                              void* d_out, int out_size, void* d_ws, size_t ws_size,
                              hipStream_t stream) {
    const float* x    = (const float*)d_in[0];
    const float* grid = (const float*)d_in[1];
    const float* kern = (const float*)d_in[2];
    float* out        = (float*)d_out;
    float* ws         = (float*)d_ws;

    precompute_kernel<<<dim3(kBD), dim3(kT), 0, stream>>>(x, kern, ws);
    interp_kernel<<<dim3(kBD), dim3(kTH), 0, stream>>>(x, grid, ws, out);
}

// Round 4
// 80.140 us; speedup vs baseline: 1.0405x; 1.0405x over previous
//
#include <hip/hip_runtime.h>
#include <math.h>

// single_channel_interp (B=8, D=64, T=512, O=256) — R3
// Kill the shared-pipe broadcast: NO LDS / NO VMEM in the hot loop.
// Each wave loads its 128-t chunk coalesced into VGPRs (t,m,v -> u,w,v),
// then broadcasts each t's (u,w,v) to SGPRs via v_readlane (per-SIMD VALU).
// Each lane owns 2 o's; per-lane constant c=-a2*g^2 dropped from the loop
// (shift-invariance), reapplied only to the logsumexp output.
//   arg' = w(t)*g + u(t);  e1 = exp2(arg');  e10 = exp2(10*arg')
//   l+=e1; y+=e1*v; q+=e10; z+=e10*v;   y/l, z/q shift-invariant;
//   w_out = (log2(l') + c) * ln2.
// Block = 512 threads = 8 waves = (2 o-halves) x (4 t-chunks); grid = 512 (b,d).

namespace {
constexpr int kB = 8, kD = 64, kT = 512, kO = 256;
constexpr float kLOG2E = 1.4426950408889634f;
constexpr float kLN2   = 0.6931471805599453f;
constexpr int kTH = 512;          // 8 waves
}

__device__ __forceinline__ float rlane(float v, int l) {
    return __int_as_float(__builtin_amdgcn_readlane(__float_as_int(v), l));
}

__global__ __launch_bounds__(kTH, 4) void interp_kernel(
    const float* __restrict__ x,     // (B, 3D, T)
    const float* __restrict__ grid,  // (B, O)
    const float* __restrict__ kern,  // (D,)
    float* __restrict__ out)         // (B, 3D, O)
{
    __shared__ float sp[4][4][kO];   // [t-chunk][quantity][o] — epilogue only

    const int tid  = threadIdx.x;
    const int lane = tid & 63;
    const int wv   = tid >> 6;       // 0..7
    const int ow   = wv & 1;         // o-half
    const int tw   = wv >> 1;        // t-chunk 0..3
    const int o0   = ow * 128 + lane;        // this lane's two o's: o0, o0+64
    const int t0   = tw * 128;

    const int bd = blockIdx.x;
    const int b  = bd >> 6;
    const int d  = bd & (kD - 1);

    const float* base = x + (size_t)b * (3 * kD * kT);
    const float* Vrow = base + (size_t)d * kT;
    const float* Mrow = base + (size_t)(kD + d) * kT;
    const float* Trow = base + (size_t)(2 * kD + d) * kT;

    const float k     = kern[d];
    const float alpha = fmaxf(k, 0.0f) + log1pf(expf(-fabsf(k)));
    const float a2    = alpha * kLOG2E;

    // Coalesced load of this wave's 128-t chunk into VGPRs; derive u,w.
    const float tt0 = Trow[t0 + lane],      tt1 = Trow[t0 + 64 + lane];
    const float mm0 = Mrow[t0 + lane],      mm1 = Mrow[t0 + 64 + lane];
    const float vv0 = Vrow[t0 + lane],      vv1 = Vrow[t0 + 64 + lane];
    const float lm0 = __builtin_amdgcn_logf(fmaxf(mm0, 1e-30f)); // log2
    const float lm1 = __builtin_amdgcn_logf(fmaxf(mm1, 1e-30f));
    const float u0  = fmaf(-a2 * tt0, tt0, lm0);
    const float u1  = fmaf(-a2 * tt1, tt1, lm1);
    const float w0  = 2.0f * a2 * tt0;
    const float w1  = 2.0f * a2 * tt1;

    const float g0 = grid[b * kO + o0];
    const float g1 = grid[b * kO + o0 + 64];

    float l_0=0.f,l_1=0.f, y_0=0.f,y_1=0.f, q_0=0.f,q_1=0.f, z_0=0.f,z_1=0.f;

    #pragma unroll
    for (int j = 0; j < 64; ++j) {
        { const float us = rlane(u0, j), ws = rlane(w0, j), vs = rlane(vv0, j);
          const float a0 = ws * g0 + us;
          const float a1 = ws * g1 + us;
          const float e0 = __builtin_amdgcn_exp2f(a0);
          const float E0 = __builtin_amdgcn_exp2f(10.0f * a0);
          const float e1 = __builtin_amdgcn_exp2f(a1);
          const float E1 = __builtin_amdgcn_exp2f(10.0f * a1);
          l_0 += e0; y_0 = fmaf(e0, vs, y_0); q_0 += E0; z_0 = fmaf(E0, vs, z_0);
          l_1 += e1; y_1 = fmaf(e1, vs, y_1); q_1 += E1; z_1 = fmaf(E1, vs, z_1); }
        { const float us = rlane(u1, j), ws = rlane(w1, j), vs = rlane(vv1, j);
          const float a0 = ws * g0 + us;
          const float a1 = ws * g1 + us;
          const float e0 = __builtin_amdgcn_exp2f(a0);
          const float E0 = __builtin_amdgcn_exp2f(10.0f * a0);
          const float e1 = __builtin_amdgcn_exp2f(a1);
          const float E1 = __builtin_amdgcn_exp2f(10.0f * a1);
          l_0 += e0; y_0 = fmaf(e0, vs, y_0); q_0 += E0; z_0 = fmaf(E0, vs, z_0);
          l_1 += e1; y_1 = fmaf(e1, vs, y_1); q_1 += E1; z_1 = fmaf(E1, vs, z_1); }
    }

    // Combine the 4 t-chunks through LDS (epilogue only; tiny).
    sp[tw][0][o0] = l_0;  sp[tw][0][o0 + 64] = l_1;
    sp[tw][1][o0] = y_0;  sp[tw][1][o0 + 64] = y_1;
    sp[tw][2][o0] = q_0;  sp[tw][2][o0 + 64] = q_1;
    sp[tw][3][o0] = z_0;  sp[tw][3][o0 + 64] = z_1;
    __syncthreads();

    if (tw == 0) {
        float L0=0.f,L1=0.f, Y0=0.f,Y1=0.f, Q0=0.f,Q1=0.f, Z0=0.f,Z1=0.f;
        #pragma unroll
        for (int j = 0; j < 4; ++j) {
            L0 += sp[j][0][o0]; Y0 += sp[j][1][o0];
            Q0 += sp[j][2][o0]; Z0 += sp[j][3][o0];
            L1 += sp[j][0][o0 + 64]; Y1 += sp[j][1][o0 + 64];
            Q1 += sp[j][2][o0 + 64]; Z1 += sp[j][3][o0 + 64];
        }
        const float c0 = -a2 * g0 * g0;       // shift we dropped in the loop
        const float c1 = -a2 * g1 * g1;
        const float w0o = (__builtin_amdgcn_logf(L0) + c0) * kLN2;
        const float w1o = (__builtin_amdgcn_logf(L1) + c1) * kLN2;
        float* ob = out + (size_t)b * (3 * kD * kO);
        ob[(size_t)d * kO + o0]                 = Y0 / L0;
        ob[(size_t)d * kO + o0 + 64]            = Y1 / L1;
        ob[(size_t)(kD + d) * kO + o0]          = w0o;
        ob[(size_t)(kD + d) * kO + o0 + 64]     = w1o;
        ob[(size_t)(2 * kD + d) * kO + o0]      = Z0 / Q0;
        ob[(size_t)(2 * kD + d) * kO + o0 + 64] = Z1 / Q1;
    }
}

extern "C" void kernel_launch(void* const* d_in, const int* in_sizes, int n_in,
                              void* d_out, int out_size, void* d_ws, size_t ws_size,
                              hipStream_t stream) {
    const float* x    = (const float*)d_in[0];
    const float* grid = (const float*)d_in[1];
    const float* kern = (const float*)d_in[2];
    float* out        = (float*)d_out;
    interp_kernel<<<dim3(kB * kD), dim3(kTH), 0, stream>>>(x, grid, kern, out);
}

// Round 5
// 76.179 us; speedup vs baseline: 1.0946x; 1.0520x over previous
//
#include <hip/hip_runtime.h>
#include <math.h>

// single_channel_interp (B=8, D=64, T=512, O=256) — R4
// Single kernel; 512 blocks (one per (b,d)) x 512 threads (8 waves).
// wave = (o-half = wv&1, t-quarter = wv>>1); each lane owns 2 o's
// (o0 = (wv&1)*128+lane, o1 = o0+64) -> LDS broadcast reads amortized 2x,
// halving the LDS-pipe occupancy that bounded R1 (~15.4 -> ~7.7 us/CU).
// Staging is log-free: mask in {0,1} => log2(max(m,1e-30)) = fma(m,C,-C),
// C = 99.6578 = -log2(1e-30), exact at both mask values.
// Hot loop per (o,t): arg = w(t)*g + u(t) + c;  e1 = exp2(arg);
// e10 = exp2(10*arg);  l+=e1; y+=e1*v; q+=e10; z+=e10*v.  (c kept in-loop
// for accuracy: R1 absmax 4.9e-4 vs R3's shift-dropped 3.1e-2.)

namespace {
constexpr int kB = 8, kD = 64, kT = 512, kO = 256;
constexpr int kTH = 512;          // 8 waves
constexpr float kLOG2E = 1.4426950408889634f;
constexpr float kLN2   = 0.6931471805599453f;
constexpr float kLM    = 99.65784284662087f;   // -log2(1e-30)
}

__global__ __launch_bounds__(kTH, 4) void interp_kernel(
    const float* __restrict__ x,     // (B, 3D, T)
    const float* __restrict__ grid,  // (B, O)
    const float* __restrict__ kern,  // (D,)
    float* __restrict__ out)         // (B, 3D, O)
{
    // [0:512)=u, [512:1024)=w, [1024:1536)=v during the loop;
    // whole 16KB reused as partials [tq][4][256] in the epilogue.
    __shared__ __align__(16) float smem[4096];
    float* s_u = smem;
    float* s_w = smem + kT;
    float* s_v = smem + 2 * kT;

    const int tid  = threadIdx.x;
    const int lane = tid & 63;
    const int wv   = tid >> 6;       // 0..7
    const int ow   = wv & 1;         // o-half
    const int tq   = wv >> 1;        // t-quarter 0..3
    const int o0   = ow * 128 + lane;
    const int o1   = o0 + 64;

    const int bd = blockIdx.x;
    const int b  = bd >> 6;
    const int d  = bd & (kD - 1);

    const float* base = x + (size_t)b * (3 * kD * kT);
    const float* Vrow = base + (size_t)d * kT;
    const float* Mrow = base + (size_t)(kD + d) * kT;
    const float* Trow = base + (size_t)(2 * kD + d) * kT;

    const float k     = kern[d];
    const float alpha = fmaxf(k, 0.0f) + log1pf(expf(-fabsf(k)));
    const float a2    = alpha * kLOG2E;

    // Stage u,w,v (thread i <-> t=i, coalesced; no logs needed).
    {
        const float tt = Trow[tid];
        const float mm = Mrow[tid];
        const float lm = fmaf(mm, kLM, -kLM);   // log2(max(m,1e-30)), exact
        s_u[tid] = fmaf(-a2 * tt, tt, lm);
        s_w[tid] = 2.0f * a2 * tt;
        s_v[tid] = Vrow[tid];
    }
    __syncthreads();

    const float g0 = grid[b * kO + o0];
    const float g1 = grid[b * kO + o1];
    const float c0 = -a2 * g0 * g0;
    const float c1 = -a2 * g1 * g1;

    float l_0=0.f,l_1=0.f, y_0=0.f,y_1=0.f, q_0=0.f,q_1=0.f, z_0=0.f,z_1=0.f;

    const int t0 = tq * 128;
    #pragma unroll 2
    for (int t = t0; t < t0 + 128; t += 4) {
        // All 64 lanes read the same LDS address -> broadcast, conflict-free.
        const float4 uu = *(const float4*)(s_u + t);
        const float4 ww = *(const float4*)(s_w + t);
        const float4 vv = *(const float4*)(s_v + t);

        #pragma unroll
        for (int j = 0; j < 4; ++j) {
            const float u = (&uu.x)[j], w = (&ww.x)[j], v = (&vv.x)[j];
            const float a0 = fmaf(w, g0, u) + c0;
            const float a1 = fmaf(w, g1, u) + c1;
            const float e0 = __builtin_amdgcn_exp2f(a0);
            const float E0 = __builtin_amdgcn_exp2f(10.0f * a0);
            const float e1 = __builtin_amdgcn_exp2f(a1);
            const float E1 = __builtin_amdgcn_exp2f(10.0f * a1);
            l_0 += e0; y_0 = fmaf(e0, v, y_0); q_0 += E0; z_0 = fmaf(E0, v, z_0);
            l_1 += e1; y_1 = fmaf(e1, v, y_1); q_1 += E1; z_1 = fmaf(E1, v, z_1);
        }
    }

    // Reuse smem for partials: [tq][quantity][o].
    __syncthreads();
    float (*sp)[4][kO] = (float (*)[4][kO])smem;
    sp[tq][0][o0] = l_0;  sp[tq][0][o1] = l_1;
    sp[tq][1][o0] = y_0;  sp[tq][1][o1] = y_1;
    sp[tq][2][o0] = q_0;  sp[tq][2][o1] = q_1;
    sp[tq][3][o0] = z_0;  sp[tq][3][o1] = z_1;
    __syncthreads();

    if (tq == 0) {
        float L0=0.f,L1=0.f, Y0=0.f,Y1=0.f, Q0=0.f,Q1=0.f, Z0=0.f,Z1=0.f;
        #pragma unroll
        for (int j = 0; j < 4; ++j) {
            L0 += sp[j][0][o0]; Y0 += sp[j][1][o0];
            Q0 += sp[j][2][o0]; Z0 += sp[j][3][o0];
            L1 += sp[j][0][o1]; Y1 += sp[j][1][o1];
            Q1 += sp[j][2][o1]; Z1 += sp[j][3][o1];
        }
        const float w0o = __builtin_amdgcn_logf(L0) * kLN2;  // logsumexp, shift=0
        const float w1o = __builtin_amdgcn_logf(L1) * kLN2;
        float* ob = out + (size_t)b * (3 * kD * kO);
        ob[(size_t)d * kO + o0]            = Y0 / L0;
        ob[(size_t)d * kO + o1]            = Y1 / L1;
        ob[(size_t)(kD + d) * kO + o0]     = w0o;
        ob[(size_t)(kD + d) * kO + o1]     = w1o;
        ob[(size_t)(2 * kD + d) * kO + o0] = Z0 / Q0;
        ob[(size_t)(2 * kD + d) * kO + o1] = Z1 / Q1;
    }
}

extern "C" void kernel_launch(void* const* d_in, const int* in_sizes, int n_in,
                              void* d_out, int out_size, void* d_ws, size_t ws_size,
                              hipStream_t stream) {
    const float* x    = (const float*)d_in[0];
    const float* grid = (const float*)d_in[1];
    const float* kern = (const float*)d_in[2];
    float* out        = (float*)d_out;
    interp_kernel<<<dim3(kB * kD), dim3(kTH), 0, stream>>>(x, grid, kern, out);
}

// Round 6
// 72.476 us; speedup vs baseline: 1.1506x; 1.0511x over previous
//
#include <hip/hip_runtime.h>
#include <math.h>

// single_channel_interp (B=8, D=64, T=512, O=256) — R5
// R4 + block-level mask compaction: ~30% of t's have mask==0 and contribute
// exp2(-~100) ~= 1e-30 (exactly 0 at fp32 vs O(100) sums). Compact (u,w,v)
// to live entries at staging (ballot + wave-count prefix scan), pad to a
// multiple of 16 with neutral entries (u=-500 -> exp2 flushes to 0), and
// loop over padded/4 per t-quarter. ~28% less hot-loop work, bit-identical
// output. Inner math grouped as float2 to invite v_pk_*_f32 packed ops.

namespace {
constexpr int kB = 8, kD = 64, kT = 512, kO = 256;
constexpr int kTH = 512;          // 8 waves
constexpr float kLOG2E = 1.4426950408889634f;
constexpr float kLN2   = 0.6931471805599453f;
constexpr float kLM    = 99.65784284662087f;   // -log2(1e-30)
}

__device__ __forceinline__ float2 pkfma(float2 a, float b, float2 c) {
    return make_float2(fmaf(a.x, b, c.x), fmaf(a.y, b, c.y));
}
__device__ __forceinline__ float2 pkadd(float2 a, float2 b) {
    return make_float2(a.x + b.x, a.y + b.y);
}

__global__ __launch_bounds__(kTH, 4) void interp_kernel(
    const float* __restrict__ x,     // (B, 3D, T)
    const float* __restrict__ grid,  // (B, O)
    const float* __restrict__ kern,  // (D,)
    float* __restrict__ out)         // (B, 3D, O)
{
    // [0:512)=u, [512:1024)=w, [1024:1536)=v during the loop;
    // reused as partials [tq][4][256] (4096 floats) in the epilogue.
    __shared__ __align__(16) float smem[4096 + 8];
    float* s_u   = smem;
    float* s_w   = smem + kT;
    float* s_v   = smem + 2 * kT;
    float* s_cnt = smem + 4096;     // 8 per-wave live counts

    const int tid  = threadIdx.x;
    const int lane = tid & 63;
    const int wv   = tid >> 6;       // 0..7
    const int ow   = wv & 1;         // o-half
    const int tq   = wv >> 1;        // t-quarter 0..3
    const int o0   = ow * 128 + lane;
    const int o1   = o0 + 64;

    const int bd = blockIdx.x;
    const int b  = bd >> 6;
    const int d  = bd & (kD - 1);

    const float* base = x + (size_t)b * (3 * kD * kT);
    const float* Vrow = base + (size_t)d * kT;
    const float* Mrow = base + (size_t)(kD + d) * kT;
    const float* Trow = base + (size_t)(2 * kD + d) * kT;

    const float k     = kern[d];
    const float alpha = fmaxf(k, 0.0f) + log1pf(expf(-fabsf(k)));
    const float a2    = alpha * kLOG2E;

    // ---- Stage + compact (thread i <-> t=i, coalesced loads) ----
    const float tt = Trow[tid];
    const float mm = Mrow[tid];
    const float vv = Vrow[tid];
    const bool keep = (mm != 0.0f);
    const unsigned long long ball = __ballot(keep);
    if (lane == 0) s_cnt[wv] = (float)__popcll(ball);
    __syncthreads();

    int bsum = 0, total = 0;
    #pragma unroll
    for (int j = 0; j < 8; ++j) {
        const int c = (int)s_cnt[j];
        bsum  += (j < wv) ? c : 0;
        total += c;
    }
    const int padded = (total + 15) & ~15;           // multiple of 16 (<=512)

    if (keep) {
        const int pos = bsum + __popcll(ball & ((1ull << lane) - 1ull));
        s_u[pos] = fmaf(-a2 * tt, tt, 0.0f);         // live => mask==1 => lm=0
        s_w[pos] = 2.0f * a2 * tt;
        s_v[pos] = vv;
    }
    if (tid >= total && tid < padded) {              // neutral padding
        s_u[tid] = -500.0f;                          // exp2 -> 0 (also x10)
        s_w[tid] = 0.0f;
        s_v[tid] = 0.0f;
    }
    __syncthreads();

    const float g0 = grid[b * kO + o0];
    const float g1 = grid[b * kO + o1];
    const float2 cc = make_float2(-a2 * g0 * g0, -a2 * g1 * g1);

    float2 acc_l = make_float2(0.f, 0.f), acc_y = make_float2(0.f, 0.f);
    float2 acc_q = make_float2(0.f, 0.f), acc_z = make_float2(0.f, 0.f);

    const int chunk = padded >> 2;                   // multiple of 4
    const int t0 = tq * chunk;
    for (int t = t0; t < t0 + chunk; t += 4) {
        // All 64 lanes read the same LDS address -> broadcast, conflict-free.
        const float4 uu = *(const float4*)(s_u + t);
        const float4 ww = *(const float4*)(s_w + t);
        const float4 vs = *(const float4*)(s_v + t);

        #pragma unroll
        for (int j = 0; j < 4; ++j) {
            const float u = (&uu.x)[j], w = (&ww.x)[j], v = (&vs.x)[j];
            const float2 a = pkadd(pkfma(make_float2(g0, g1), w,
                                         make_float2(u, u)), cc);
            const float2 e = make_float2(__builtin_amdgcn_exp2f(a.x),
                                         __builtin_amdgcn_exp2f(a.y));
            const float2 E = make_float2(__builtin_amdgcn_exp2f(10.0f * a.x),
                                         __builtin_amdgcn_exp2f(10.0f * a.y));
            acc_l = pkadd(acc_l, e);
            acc_y = pkfma(e, v, acc_y);
            acc_q = pkadd(acc_q, E);
            acc_z = pkfma(E, v, acc_z);
        }
    }

    // ---- Combine the 4 t-quarters through LDS ----
    __syncthreads();
    float (*sp)[4][kO] = (float (*)[4][kO])smem;
    sp[tq][0][o0] = acc_l.x;  sp[tq][0][o1] = acc_l.y;
    sp[tq][1][o0] = acc_y.x;  sp[tq][1][o1] = acc_y.y;
    sp[tq][2][o0] = acc_q.x;  sp[tq][2][o1] = acc_q.y;
    sp[tq][3][o0] = acc_z.x;  sp[tq][3][o1] = acc_z.y;
    __syncthreads();

    if (tq == 0) {
        float L0=0.f,L1=0.f, Y0=0.f,Y1=0.f, Q0=0.f,Q1=0.f, Z0=0.f,Z1=0.f;
        #pragma unroll
        for (int j = 0; j < 4; ++j) {
            L0 += sp[j][0][o0]; Y0 += sp[j][1][o0];
            Q0 += sp[j][2][o0]; Z0 += sp[j][3][o0];
            L1 += sp[j][0][o1]; Y1 += sp[j][1][o1];
            Q1 += sp[j][2][o1]; Z1 += sp[j][3][o1];
        }
        const float w0o = __builtin_amdgcn_logf(L0) * kLN2;  // logsumexp, shift=0
        const float w1o = __builtin_amdgcn_logf(L1) * kLN2;
        float* ob = out + (size_t)b * (3 * kD * kO);
        ob[(size_t)d * kO + o0]            = Y0 / L0;
        ob[(size_t)d * kO + o1]            = Y1 / L1;
        ob[(size_t)(kD + d) * kO + o0]     = w0o;
        ob[(size_t)(kD + d) * kO + o1]     = w1o;
        ob[(size_t)(2 * kD + d) * kO + o0] = Z0 / Q0;
        ob[(size_t)(2 * kD + d) * kO + o1] = Z1 / Q1;
    }
}

extern "C" void kernel_launch(void* const* d_in, const int* in_sizes, int n_in,
                              void* d_out, int out_size, void* d_ws, size_t ws_size,
                              hipStream_t stream) {
    const float* x    = (const float*)d_in[0];
    const float* grid = (const float*)d_in[1];
    const float* kern = (const float*)d_in[2];
    float* out        = (float*)d_out;
    interp_kernel<<<dim3(kB * kD), dim3(kTH), 0, stream>>>(x, grid, kern, out);
}